// Round 1
// baseline (150.709 us; speedup 1.0000x reference)
//
#include <hip/hip_runtime.h>

typedef float f32x4 __attribute__((ext_vector_type(4)));
typedef int   i32x4 __attribute__((ext_vector_type(4)));

#define NB 8
#define NN 1024
#define NH 768
#define NEGC 1000000000000.0f

// ---------------- Kernel A ----------------
// grid: NB * (NN/16) = 512 blocks, 256 threads.
// Computes x = inputs@W1 + b1 for 16 rows, RoPE -> qw (B,N,64) and kwT (B,64,N),
// and biasT (B,24,N) = ((x@W2 + b2)/2) transposed.
__global__ __launch_bounds__(256) void ka(const float* __restrict__ in,
                                          const float* __restrict__ W1,
                                          const float* __restrict__ b1,
                                          const float* __restrict__ W2,
                                          const float* __restrict__ b2,
                                          float* __restrict__ qw,
                                          float* __restrict__ kwT,
                                          float* __restrict__ biasT) {
    __shared__ float in_s[16 * NH];      // 48 KB
    __shared__ float x_s[16 * 129];      // padded stride 129
    const int t   = threadIdx.x;
    const int blk = blockIdx.x;
    const int b   = blk >> 6;            // 64 m-tiles per batch
    const int m0  = (blk & 63) * 16;

    const float* inrow = in + ((size_t)(b * NN) + m0) * NH;
    for (int idx = t * 4; idx < 16 * NH; idx += 1024) {
        *(f32x4*)&in_s[idx] = *(const f32x4*)&inrow[idx];
    }
    __syncthreads();

    const int j     = t & 127;
    const int half  = t >> 7;            // wave-uniform
    const int rbase = half * 8;

    float acc[8];
    {
        const float bj = b1[j];
#pragma unroll
        for (int r = 0; r < 8; r++) acc[r] = bj;
    }
    for (int k = 0; k < NH; k += 4) {
        const float w0 = W1[(k + 0) * 128 + j];
        const float w1 = W1[(k + 1) * 128 + j];
        const float w2 = W1[(k + 2) * 128 + j];
        const float w3 = W1[(k + 3) * 128 + j];
#pragma unroll
        for (int r = 0; r < 8; r++) {
            const f32x4 iv = *(const f32x4*)&in_s[(rbase + r) * NH + k];
            acc[r] = fmaf(iv.x, w0, acc[r]);
            acc[r] = fmaf(iv.y, w1, acc[r]);
            acc[r] = fmaf(iv.z, w2, acc[r]);
            acc[r] = fmaf(iv.w, w3, acc[r]);
        }
    }

    // stash x for bias compute
#pragma unroll
    for (int r = 0; r < 8; r++) x_s[(rbase + r) * 129 + j] = acc[r];

    // RoPE: x-channel j pairs with j^2. qw[i]=x[2i] (even j), kw[i]=x[2i+1] (odd j).
    // pair index u = j>>2, inv = 10000^(-u/32); lower of pair (j&2==0) gets -partner*sin.
    const float inv  = __powf(10000.0f, -(float)(j >> 2) * (1.0f / 32.0f));
    const int   i_el = j >> 1;
    const bool  isq  = (j & 1) == 0;
#pragma unroll
    for (int r = 0; r < 8; r++) {
        const int   m       = m0 + rbase + r;
        const float partner = __shfl_xor(acc[r], 2);
        float sa, ca;
        __sincosf((float)m * inv, &sa, &ca);
        const float rv = acc[r] * ca + ((j & 2) ? partner : -partner) * sa;
        if (isq) qw[((size_t)(b * NN) + m) * 64 + i_el] = rv;
        else     kwT[((size_t)b * 64 + i_el) * NN + m]  = rv;
    }
    __syncthreads();

    // bias: 16 rows x 24 cols
    for (int o = t; o < 16 * 24; o += 256) {
        const int r  = o / 24;
        const int j2 = o - r * 24;
        float s = b2[j2];
#pragma unroll 4
        for (int k = 0; k < 128; k++) s = fmaf(x_s[r * 129 + k], W2[k * 24 + j2], s);
        biasT[((size_t)b * 24 + j2) * NN + m0 + r] = s * 0.5f;
    }
}

// ---------------- Kernel B ----------------
// grid: NB * (NN/8) = 1024 blocks, 256 threads. Block = (batch b, 8 m-rows, all n).
// Thread owns n = 4t..4t+3. out[b,h,m,n] = dot(qw[m],kw[n])/8 + be[h][n] + bo[h][m] - masks.
__global__ __launch_bounds__(256) void kb(const float* __restrict__ qw,
                                          const float* __restrict__ kwT,
                                          const float* __restrict__ biasT,
                                          const int* __restrict__ am,
                                          float* __restrict__ out) {
    __shared__ float qw_s[8 * 64];
    __shared__ float bo_s[12 * 8];
    __shared__ float amm_s[8];
    const int t   = threadIdx.x;
    const int blk = blockIdx.x;
    const int b   = blk >> 7;
    const int m0  = (blk & 127) * 8;

    {
        const float* src = qw + ((size_t)(b * NN) + m0) * 64;
        qw_s[t]       = src[t];
        qw_s[t + 256] = src[t + 256];
        if (t < 96) {
            const int h = t >> 3, m = t & 7;
            bo_s[t] = biasT[((size_t)b * 24 + 2 * h + 1) * NN + m0 + m];
        }
        if (t < 8) amm_s[t] = (float)am[b * NN + m0 + t];
    }
    __syncthreads();

    const int n0 = t * 4;

    f32x4 acc[8];
#pragma unroll
    for (int m = 0; m < 8; m++) acc[m] = (f32x4)0.0f;

    const float* kbase = kwT + (size_t)b * 64 * NN + n0;
    for (int i = 0; i < 64; i += 4) {
        const f32x4 kv0 = *(const f32x4*)(kbase + (size_t)(i + 0) * NN);
        const f32x4 kv1 = *(const f32x4*)(kbase + (size_t)(i + 1) * NN);
        const f32x4 kv2 = *(const f32x4*)(kbase + (size_t)(i + 2) * NN);
        const f32x4 kv3 = *(const f32x4*)(kbase + (size_t)(i + 3) * NN);
#pragma unroll
        for (int m = 0; m < 8; m++) {
            const f32x4 qv = *(const f32x4*)&qw_s[m * 64 + i];
            acc[m] += qv.x * kv0;
            acc[m] += qv.y * kv1;
            acc[m] += qv.z * kv2;
            acc[m] += qv.w * kv3;
        }
    }

    // fold scale + pad mask + causal mask into acc
    const i32x4 a4 = *(const i32x4*)(am + b * NN + n0);
    f32x4 amn;
    amn.x = (float)a4.x; amn.y = (float)a4.y; amn.z = (float)a4.z; amn.w = (float)a4.w;
#pragma unroll
    for (int m = 0; m < 8; m++) {
        const int   mg   = m0 + m;
        const float ammv = amm_s[m];
        f32x4 msk;
        msk.x = (1.0f - ammv * amn.x) + ((n0 + 0 < mg) ? 1.0f : 0.0f);
        msk.y = (1.0f - ammv * amn.y) + ((n0 + 1 < mg) ? 1.0f : 0.0f);
        msk.z = (1.0f - ammv * amn.z) + ((n0 + 2 < mg) ? 1.0f : 0.0f);
        msk.w = (1.0f - ammv * amn.w) + ((n0 + 3 < mg) ? 1.0f : 0.0f);
        acc[m] = acc[m] * 0.125f - msk * NEGC;
    }

    float* outb = out + (size_t)b * 12 * NN * NN + (size_t)m0 * NN + n0;
#pragma unroll
    for (int h = 0; h < 12; h++) {
        const f32x4 be = *(const f32x4*)(biasT + ((size_t)b * 24 + 2 * h) * NN + n0);
#pragma unroll
        for (int m = 0; m < 8; m++) {
            const float bo = bo_s[h * 8 + m];
            const f32x4 v  = acc[m] + be + bo;
            __builtin_nontemporal_store(v, (f32x4*)(outb + (size_t)h * NN * NN + (size_t)m * NN));
        }
    }
}

extern "C" void kernel_launch(void* const* d_in, const int* in_sizes, int n_in,
                              void* d_out, int out_size, void* d_ws, size_t ws_size,
                              hipStream_t stream) {
    const float* in  = (const float*)d_in[0];
    const int*   am  = (const int*)d_in[1];
    const float* W1  = (const float*)d_in[2];
    const float* b1  = (const float*)d_in[3];
    const float* W2  = (const float*)d_in[4];
    const float* b2  = (const float*)d_in[5];
    float*       out = (float*)d_out;

    float* ws    = (float*)d_ws;
    float* qw    = ws;                       // 8*1024*64  = 524288 floats
    float* kwT   = ws + (size_t)NB * NN * 64;           // 524288 floats
    float* biasT = ws + (size_t)2 * NB * NN * 64;       // 8*24*1024 = 196608 floats
    // total ws use: ~4.98 MB

    hipLaunchKernelGGL(ka, dim3(NB * (NN / 16)), dim3(256), 0, stream,
                       in, W1, b1, W2, b2, qw, kwT, biasT);
    hipLaunchKernelGGL(kb, dim3(NB * (NN / 8)), dim3(256), 0, stream,
                       qw, kwT, biasT, am, out);
}

// Round 2
// 147.938 us; speedup vs baseline: 1.0187x; 1.0187x over previous
//
#include <hip/hip_runtime.h>

typedef float f32x4 __attribute__((ext_vector_type(4)));
typedef int   i32x4 __attribute__((ext_vector_type(4)));

#define NB 8
#define NN 1024
#define NH 768
#define NEGC 1000000000000.0f

// ---------------- Kernel A v2 ----------------
// grid: 8192/32 = 256 blocks, 512 threads.
// Block handles 32 rows (one batch slice). Computes x = in@W1+b1 (f32 VALU,
// R2xC4 register blocking), RoPE via LDS partner reads, bias = (x@W2+b2)/2.
// All outputs transposed through LDS -> coalesced stores.
__global__ __launch_bounds__(512) void ka(const float* __restrict__ in,
                                          const float* __restrict__ W1,
                                          const float* __restrict__ b1,
                                          const float* __restrict__ W2,
                                          const float* __restrict__ b2,
                                          float* __restrict__ qw,
                                          float* __restrict__ kwT,
                                          float* __restrict__ biasT) {
    __shared__ float buf[32 * 772];   // in_s staging (stride 772); reused as qk_s[32][132] + bias_s
    __shared__ float x_s[32 * 132];   // x tile, stride 132

    const int t   = threadIdx.x;
    const int blk = blockIdx.x;
    const int b   = blk >> 5;
    const int m0  = (blk & 31) * 32;

    // ---- stage input tile 32 x 768 (padded stride 772) ----
    const float* inrow = in + ((size_t)(b * NN) + m0) * NH;
    for (int idx = t; idx < 32 * 192; idx += 512) {
        const int r  = idx / 192;
        const int kv = (idx - r * 192) * 4;
        *(f32x4*)&buf[r * 772 + kv] = *(const f32x4*)&inrow[r * NH + kv];
    }
    __syncthreads();

    // ---- GEMM: x[r][j] = sum_k in[r][k] * W1[k][j] + b1[j] ----
    {
        const int jg = t & 31;        // 32 col groups of 4
        const int rg = t >> 5;        // 16 row groups of 2
        const int j0 = jg * 4;
        const int r0 = rg * 2;
        const f32x4 bv = *(const f32x4*)&b1[j0];
        f32x4 acc0 = bv, acc1 = bv;
        const float* in0 = &buf[r0 * 772];
        const float* in1 = &buf[(r0 + 1) * 772];
#pragma unroll 2
        for (int k = 0; k < NH; k += 4) {
            const f32x4 w0 = *(const f32x4*)&W1[(k + 0) * 128 + j0];
            const f32x4 w1 = *(const f32x4*)&W1[(k + 1) * 128 + j0];
            const f32x4 w2 = *(const f32x4*)&W1[(k + 2) * 128 + j0];
            const f32x4 w3 = *(const f32x4*)&W1[(k + 3) * 128 + j0];
            const f32x4 a0 = *(const f32x4*)&in0[k];
            const f32x4 a1 = *(const f32x4*)&in1[k];
            acc0 += a0.x * w0; acc0 += a0.y * w1; acc0 += a0.z * w2; acc0 += a0.w * w3;
            acc1 += a1.x * w0; acc1 += a1.y * w1; acc1 += a1.z * w2; acc1 += a1.w * w3;
        }
        *(f32x4*)&x_s[(r0 + 0) * 132 + j0] = acc0;
        *(f32x4*)&x_s[(r0 + 1) * 132 + j0] = acc1;
    }
    __syncthreads();   // x_s ready; buf (in_s) free for reuse

    float* qk_s   = buf;              // [32][132]
    float* bias_s = buf + 8192;       // [24][33]

    // ---- RoPE: 128 channels x 4 row-groups of 8 ----
    {
        const int jj  = t & 127;
        const int r0b = (t >> 7) * 8;
        const float inv = __powf(10000.0f, -(float)(jj >> 2) * (1.0f / 32.0f));
        const int col = (jj & 1) ? (64 + (jj >> 1)) : (jj >> 1);
        const float sgn = (jj & 2) ? 1.0f : -1.0f;
#pragma unroll
        for (int r = 0; r < 8; r++) {
            const int   rr = r0b + r;
            const float xv = x_s[rr * 132 + jj];
            const float pv = x_s[rr * 132 + (jj ^ 2)];
            float sa, ca;
            __sincosf((float)(m0 + rr) * inv, &sa, &ca);
            qk_s[rr * 132 + col] = xv * ca + sgn * pv * sa;
        }
    }
    __syncthreads();

    // ---- qw store: 32 rows x 64 ch, coalesced 256B runs ----
    {
        const int r  = t >> 4;
        const int i4 = (t & 15) * 4;
        const f32x4 v = *(const f32x4*)&qk_s[r * 132 + i4];
        *(f32x4*)&qw[((size_t)(b * NN) + m0 + r) * 64 + i4] = v;
    }
    // ---- kwT store: 64 ch x 32 m, coalesced 128B runs per channel ----
    {
        const int ch = t >> 3;
        const int mg = (t & 7) * 4;
        f32x4 v;
        v.x = qk_s[(mg + 0) * 132 + 64 + ch];
        v.y = qk_s[(mg + 1) * 132 + 64 + ch];
        v.z = qk_s[(mg + 2) * 132 + 64 + ch];
        v.w = qk_s[(mg + 3) * 132 + 64 + ch];
        *(f32x4*)&kwT[((size_t)b * 64 + ch) * NN + m0 + mg] = v;
    }
    // ---- bias: 32 rows x 24 cols -> bias_s[c][r] ----
    for (int o = t; o < 32 * 24; o += 512) {
        const int r = o & 31;
        const int c = o >> 5;
        float s = b2[c];
#pragma unroll 4
        for (int k = 0; k < 128; k += 4) {
            const f32x4 xv = *(const f32x4*)&x_s[r * 132 + k];
            s = fmaf(xv.x, W2[(k + 0) * 24 + c], s);
            s = fmaf(xv.y, W2[(k + 1) * 24 + c], s);
            s = fmaf(xv.z, W2[(k + 2) * 24 + c], s);
            s = fmaf(xv.w, W2[(k + 3) * 24 + c], s);
        }
        bias_s[c * 33 + r] = s * 0.5f;
    }
    __syncthreads();
    // ---- biasT store: 24 ch x 32 m, coalesced ----
    if (t < 192) {
        const int ch = t >> 3;
        const int mg = (t & 7) * 4;
        const f32x4 v = *(const f32x4*)&bias_s[ch * 33 + mg];
        *(f32x4*)&biasT[((size_t)b * 24 + ch) * NN + m0 + mg] = v;
    }
}

// ---------------- Kernel B ----------------
// grid: NB * (NN/8) = 1024 blocks, 256 threads. Block = (batch b, 8 m-rows, all n).
__global__ __launch_bounds__(256) void kb(const float* __restrict__ qw,
                                          const float* __restrict__ kwT,
                                          const float* __restrict__ biasT,
                                          const int* __restrict__ am,
                                          float* __restrict__ out) {
    __shared__ float qw_s[8 * 64];
    __shared__ float bo_s[12 * 8];
    __shared__ float amm_s[8];
    const int t   = threadIdx.x;
    const int blk = blockIdx.x;
    const int b   = blk >> 7;
    const int m0  = (blk & 127) * 8;

    {
        const float* src = qw + ((size_t)(b * NN) + m0) * 64;
        qw_s[t]       = src[t];
        qw_s[t + 256] = src[t + 256];
        if (t < 96) {
            const int h = t >> 3, m = t & 7;
            bo_s[t] = biasT[((size_t)b * 24 + 2 * h + 1) * NN + m0 + m];
        }
        if (t < 8) amm_s[t] = (float)am[b * NN + m0 + t];
    }
    __syncthreads();

    const int n0 = t * 4;

    f32x4 acc[8];
#pragma unroll
    for (int m = 0; m < 8; m++) acc[m] = (f32x4)0.0f;

    const float* kbase = kwT + (size_t)b * 64 * NN + n0;
    for (int i = 0; i < 64; i += 4) {
        const f32x4 kv0 = *(const f32x4*)(kbase + (size_t)(i + 0) * NN);
        const f32x4 kv1 = *(const f32x4*)(kbase + (size_t)(i + 1) * NN);
        const f32x4 kv2 = *(const f32x4*)(kbase + (size_t)(i + 2) * NN);
        const f32x4 kv3 = *(const f32x4*)(kbase + (size_t)(i + 3) * NN);
#pragma unroll
        for (int m = 0; m < 8; m++) {
            const f32x4 qv = *(const f32x4*)&qw_s[m * 64 + i];
            acc[m] += qv.x * kv0;
            acc[m] += qv.y * kv1;
            acc[m] += qv.z * kv2;
            acc[m] += qv.w * kv3;
        }
    }

    const i32x4 a4 = *(const i32x4*)(am + b * NN + n0);
    f32x4 amn;
    amn.x = (float)a4.x; amn.y = (float)a4.y; amn.z = (float)a4.z; amn.w = (float)a4.w;
#pragma unroll
    for (int m = 0; m < 8; m++) {
        const int   mg   = m0 + m;
        const float ammv = amm_s[m];
        f32x4 msk;
        msk.x = (1.0f - ammv * amn.x) + ((n0 + 0 < mg) ? 1.0f : 0.0f);
        msk.y = (1.0f - ammv * amn.y) + ((n0 + 1 < mg) ? 1.0f : 0.0f);
        msk.z = (1.0f - ammv * amn.z) + ((n0 + 2 < mg) ? 1.0f : 0.0f);
        msk.w = (1.0f - ammv * amn.w) + ((n0 + 3 < mg) ? 1.0f : 0.0f);
        acc[m] = acc[m] * 0.125f - msk * NEGC;
    }

    float* outb = out + (size_t)b * 12 * NN * NN + (size_t)m0 * NN + n0;
#pragma unroll
    for (int h = 0; h < 12; h++) {
        const f32x4 be = *(const f32x4*)(biasT + ((size_t)b * 24 + 2 * h) * NN + n0);
#pragma unroll
        for (int m = 0; m < 8; m++) {
            const float bo = bo_s[h * 8 + m];
            const f32x4 v  = acc[m] + be + bo;
            __builtin_nontemporal_store(v, (f32x4*)(outb + (size_t)h * NN * NN + (size_t)m * NN));
        }
    }
}

extern "C" void kernel_launch(void* const* d_in, const int* in_sizes, int n_in,
                              void* d_out, int out_size, void* d_ws, size_t ws_size,
                              hipStream_t stream) {
    const float* in  = (const float*)d_in[0];
    const int*   am  = (const int*)d_in[1];
    const float* W1  = (const float*)d_in[2];
    const float* b1  = (const float*)d_in[3];
    const float* W2  = (const float*)d_in[4];
    const float* b2  = (const float*)d_in[5];
    float*       out = (float*)d_out;

    float* ws    = (float*)d_ws;
    float* qw    = ws;                                  // 8*1024*64 floats
    float* kwT   = ws + (size_t)NB * NN * 64;           // 8*64*1024 floats
    float* biasT = ws + (size_t)2 * NB * NN * 64;       // 8*24*1024 floats

    hipLaunchKernelGGL(ka, dim3(8192 / 32), dim3(512), 0, stream,
                       in, W1, b1, W2, b2, qw, kwT, biasT);
    hipLaunchKernelGGL(kb, dim3(NB * (NN / 8)), dim3(256), 0, stream,
                       qw, kwT, biasT, am, out);
}

// Round 4
// 135.226 us; speedup vs baseline: 1.1145x; 1.0940x over previous
//
#include <hip/hip_runtime.h>

typedef float f32x4 __attribute__((ext_vector_type(4)));
typedef int   i32x4 __attribute__((ext_vector_type(4)));

#define NB 8
#define NN 1024
#define NH 768
#define NEGC 1000000000000.0f

// ---------------- Kernel A v3 ----------------
// grid: 256 blocks x 256 threads. Block = 32 rows.
// x = in@W1+b1 (R4xC4 register blocking), RoPE via LDS table, bias=(x@W2+b2)/2.
// All outputs coalesced through LDS transpose.
__global__ __launch_bounds__(256) void ka(const float* __restrict__ in,
                                          const float* __restrict__ W1,
                                          const float* __restrict__ b1,
                                          const float* __restrict__ W2,
                                          const float* __restrict__ b2,
                                          float* __restrict__ qw,
                                          float* __restrict__ kwT,
                                          float* __restrict__ biasT) {
    __shared__ float buf[32 * 772];   // staging (stride 772); reused as qk_s[32][132] + bias_s[24][33]
    __shared__ float x_s[32 * 132];   // x tile
    __shared__ float tab[32 * 64];    // [row][2u]=cos, [row][2u+1]=sin

    const int t   = threadIdx.x;
    const int blk = blockIdx.x;
    const int b   = blk >> 5;
    const int m0  = (blk & 31) * 32;

    // ---- stage input tile 32 x 768 ----
    const float* inrow = in + ((size_t)(b * NN) + m0) * NH;
    for (int g = t; g < 32 * 192; g += 256) {
        const int r  = g / 192;
        const int kv = (g - r * 192) * 4;
        *(f32x4*)&buf[r * 772 + kv] = *(const f32x4*)&inrow[r * NH + kv];
    }
    __syncthreads();

    // ---- sincos table: 32 rows x 32 freqs (4 per thread) ----
    for (int o = t; o < 1024; o += 256) {
        const int rr = o & 31;
        const int u  = o >> 5;
        const float inv = exp2f(-(float)u * 0.415241011861f);  // 10000^(-u/32)
        float sa, ca;
        __sincosf((float)(m0 + rr) * inv, &sa, &ca);
        tab[rr * 64 + 2 * u]     = ca;
        tab[rr * 64 + 2 * u + 1] = sa;
    }

    // ---- GEMM: R4 x C4 ----
    {
        const int j0 = (t & 31) * 4;
        const int r0 = (t >> 5) * 4;
        const f32x4 bv = *(const f32x4*)&b1[j0];
        f32x4 acc0 = bv, acc1 = bv, acc2 = bv, acc3 = bv;
        const float* a0p = &buf[(r0 + 0) * 772];
        const float* a1p = &buf[(r0 + 1) * 772];
        const float* a2p = &buf[(r0 + 2) * 772];
        const float* a3p = &buf[(r0 + 3) * 772];
#pragma unroll 2
        for (int k = 0; k < NH; k += 4) {
            const f32x4 w0 = *(const f32x4*)&W1[(k + 0) * 128 + j0];
            const f32x4 w1 = *(const f32x4*)&W1[(k + 1) * 128 + j0];
            const f32x4 w2 = *(const f32x4*)&W1[(k + 2) * 128 + j0];
            const f32x4 w3 = *(const f32x4*)&W1[(k + 3) * 128 + j0];
            const f32x4 a0 = *(const f32x4*)&a0p[k];
            const f32x4 a1 = *(const f32x4*)&a1p[k];
            const f32x4 a2 = *(const f32x4*)&a2p[k];
            const f32x4 a3 = *(const f32x4*)&a3p[k];
            acc0 += a0.x * w0; acc0 += a0.y * w1; acc0 += a0.z * w2; acc0 += a0.w * w3;
            acc1 += a1.x * w0; acc1 += a1.y * w1; acc1 += a1.z * w2; acc1 += a1.w * w3;
            acc2 += a2.x * w0; acc2 += a2.y * w1; acc2 += a2.z * w2; acc2 += a2.w * w3;
            acc3 += a3.x * w0; acc3 += a3.y * w1; acc3 += a3.z * w2; acc3 += a3.w * w3;
        }
        __syncthreads();   // everyone done reading buf
        *(f32x4*)&x_s[(r0 + 0) * 132 + j0] = acc0;
        *(f32x4*)&x_s[(r0 + 1) * 132 + j0] = acc1;
        *(f32x4*)&x_s[(r0 + 2) * 132 + j0] = acc2;
        *(f32x4*)&x_s[(r0 + 3) * 132 + j0] = acc3;
    }
    __syncthreads();   // x_s + tab ready; buf free

    float* qk_s   = buf;              // [32][132]
    float* bias_s = buf + 8192;       // [24][33]

    // ---- RoPE: 128 channels x 2 row-halves of 16 ----
    {
        const int jj  = t & 127;
        const int r0b = (t >> 7) * 16;
        const int u2  = (jj >> 2) * 2;
        const int col = (jj & 1) ? (64 + (jj >> 1)) : (jj >> 1);
        const float sgn = (jj & 2) ? 1.0f : -1.0f;
#pragma unroll
        for (int r = 0; r < 16; r++) {
            const int   rr = r0b + r;
            const float xv = x_s[rr * 132 + jj];
            const float pv = x_s[rr * 132 + (jj ^ 2)];
            const float ca = tab[rr * 64 + u2];
            const float sa = tab[rr * 64 + u2 + 1];
            qk_s[rr * 132 + col] = xv * ca + sgn * pv * sa;
        }
    }
    __syncthreads();

    // ---- qw store: 32 rows x 16 f32x4 ----
    for (int o = t; o < 512; o += 256) {
        const int r  = o >> 4;
        const int i4 = (o & 15) * 4;
        *(f32x4*)&qw[((size_t)(b * NN) + m0 + r) * 64 + i4] = *(const f32x4*)&qk_s[r * 132 + i4];
    }
    // ---- kwT store: 64 ch x 8 f32x4-of-m ----
    for (int o = t; o < 512; o += 256) {
        const int ch = o >> 3;
        const int mg = (o & 7) * 4;
        f32x4 v;
        v.x = qk_s[(mg + 0) * 132 + 64 + ch];
        v.y = qk_s[(mg + 1) * 132 + 64 + ch];
        v.z = qk_s[(mg + 2) * 132 + 64 + ch];
        v.w = qk_s[(mg + 3) * 132 + 64 + ch];
        *(f32x4*)&kwT[((size_t)b * 64 + ch) * NN + m0 + mg] = v;
    }
    // ---- bias dots: 32 rows x 24 cols ----
    for (int o = t; o < 768; o += 256) {
        const int r = o & 31;
        const int c = o >> 5;
        float s = b2[c];
#pragma unroll 4
        for (int k = 0; k < 128; k += 4) {
            const f32x4 xv = *(const f32x4*)&x_s[r * 132 + k];
            s = fmaf(xv.x, W2[(k + 0) * 24 + c], s);
            s = fmaf(xv.y, W2[(k + 1) * 24 + c], s);
            s = fmaf(xv.z, W2[(k + 2) * 24 + c], s);
            s = fmaf(xv.w, W2[(k + 3) * 24 + c], s);
        }
        bias_s[c * 33 + r] = s * 0.5f;
    }
    __syncthreads();
    // ---- biasT store ----
    if (t < 192) {
        const int ch = t >> 3;
        const int mg = (t & 7) * 4;
        *(f32x4*)&biasT[((size_t)b * 24 + ch) * NN + m0 + mg] = *(const f32x4*)&bias_s[ch * 33 + mg];
    }
}

// ---------------- Kernel B v3 ----------------
// grid: NB*256 = 2048 blocks x 256 threads. Block = (b, 4 m-rows, all n).
__global__ __launch_bounds__(256, 8) void kb(const float* __restrict__ qw,
                                             const float* __restrict__ kwT,
                                             const float* __restrict__ biasT,
                                             const int* __restrict__ am,
                                             float* __restrict__ out) {
    __shared__ float qw_s[4 * 64];
    __shared__ float bo_s[12 * 4];
    __shared__ float amm_s[4];
    const int t   = threadIdx.x;
    const int blk = blockIdx.x;
    const int b   = blk >> 8;
    const int m0  = (blk & 255) * 4;

    {
        if (t < 256) qw_s[t] = qw[((size_t)(b * NN) + m0) * 64 + t];
        if (t < 48) {
            const int h = t >> 2, m = t & 3;
            bo_s[t] = biasT[((size_t)b * 24 + 2 * h + 1) * NN + m0 + m];
        }
        if (t < 4) amm_s[t] = (float)am[b * NN + m0 + t];
    }
    __syncthreads();

    const int n0 = t * 4;

    f32x4 acc[4];
#pragma unroll
    for (int m = 0; m < 4; m++) acc[m] = (f32x4)0.0f;

    const float* kbase = kwT + (size_t)b * 64 * NN + n0;
    for (int i = 0; i < 64; i += 4) {
        const f32x4 kv0 = *(const f32x4*)(kbase + (size_t)(i + 0) * NN);
        const f32x4 kv1 = *(const f32x4*)(kbase + (size_t)(i + 1) * NN);
        const f32x4 kv2 = *(const f32x4*)(kbase + (size_t)(i + 2) * NN);
        const f32x4 kv3 = *(const f32x4*)(kbase + (size_t)(i + 3) * NN);
#pragma unroll
        for (int m = 0; m < 4; m++) {
            const f32x4 qv = *(const f32x4*)&qw_s[m * 64 + i];
            acc[m] += qv.x * kv0;
            acc[m] += qv.y * kv1;
            acc[m] += qv.z * kv2;
            acc[m] += qv.w * kv3;
        }
    }

    const i32x4 a4 = *(const i32x4*)(am + b * NN + n0);
    f32x4 amn;
    amn.x = (float)a4.x; amn.y = (float)a4.y; amn.z = (float)a4.z; amn.w = (float)a4.w;
#pragma unroll
    for (int m = 0; m < 4; m++) {
        const int   mg   = m0 + m;
        const float ammv = amm_s[m];
        f32x4 msk;
        msk.x = (1.0f - ammv * amn.x) + ((n0 + 0 < mg) ? 1.0f : 0.0f);
        msk.y = (1.0f - ammv * amn.y) + ((n0 + 1 < mg) ? 1.0f : 0.0f);
        msk.z = (1.0f - ammv * amn.z) + ((n0 + 2 < mg) ? 1.0f : 0.0f);
        msk.w = (1.0f - ammv * amn.w) + ((n0 + 3 < mg) ? 1.0f : 0.0f);
        acc[m] = acc[m] * 0.125f - msk * NEGC;
    }

    float* outb = out + (size_t)b * 12 * NN * NN + (size_t)m0 * NN + n0;
#pragma unroll
    for (int h = 0; h < 12; h++) {
        const f32x4 be = *(const f32x4*)(biasT + ((size_t)b * 24 + 2 * h) * NN + n0);
#pragma unroll
        for (int m = 0; m < 4; m++) {
            const float bo = bo_s[h * 4 + m];
            const f32x4 v  = acc[m] + be + bo;
            __builtin_nontemporal_store(v, (f32x4*)(outb + (size_t)h * NN * NN + (size_t)m * NN));
        }
    }
}

extern "C" void kernel_launch(void* const* d_in, const int* in_sizes, int n_in,
                              void* d_out, int out_size, void* d_ws, size_t ws_size,
                              hipStream_t stream) {
    const float* in  = (const float*)d_in[0];
    const int*   am  = (const int*)d_in[1];
    const float* W1  = (const float*)d_in[2];
    const float* b1  = (const float*)d_in[3];
    const float* W2  = (const float*)d_in[4];
    const float* b2  = (const float*)d_in[5];
    float*       out = (float*)d_out;

    float* ws    = (float*)d_ws;
    float* qw    = ws;                                  // 8*1024*64 floats
    float* kwT   = ws + (size_t)NB * NN * 64;           // 8*64*1024 floats
    float* biasT = ws + (size_t)2 * NB * NN * 64;       // 8*24*1024 floats

    hipLaunchKernelGGL(ka, dim3(256), dim3(256), 0, stream,
                       in, W1, b1, W2, b2, qw, kwT, biasT);
    hipLaunchKernelGGL(kb, dim3(NB * 256), dim3(256), 0, stream,
                       qw, kwT, biasT, am, out);
}